// Round 12
// baseline (688.244 us; speedup 1.0000x reference)
//
#include <hip/hip_runtime.h>
#include <hip/hip_bf16.h>

#define SEQ    2048
#define DMODEL 2048
#define NHEAD  16
#define DHEAD  128
#define TOK    4096   // B*S
#define TD     6144   // 3*D
#define FFDIM  8192

typedef __attribute__((ext_vector_type(4)))  float f32x4;
typedef __attribute__((ext_vector_type(16))) float f32x16;
typedef __attribute__((ext_vector_type(8)))  short short8v;

__device__ __forceinline__ void async_ld16(const void* src, void* lds) {
  __builtin_amdgcn_global_load_lds((const __attribute__((address_space(1))) void*)src,
                                   (__attribute__((address_space(3))) void*)lds, 16, 0, 0);
}

// pack two f32 -> one u32 of 2 bf16, explicit element order (low short = a)
__device__ __forceinline__ unsigned pk2(float a, float b) {
  union { __hip_bfloat16 h[2]; unsigned u; } p;
  p.h[0] = __float2bfloat16(a);
  p.h[1] = __float2bfloat16(b);
  return p.u;
}

// ---------------------------------------------------------------- fp32 -> bf16
__global__ __launch_bounds__(256) void f2bf_kernel(const float* __restrict__ in,
                                                   __hip_bfloat16* __restrict__ out, long n) {
  long i0 = ((long)blockIdx.x * 256 + threadIdx.x) * 8;
  long stride = (long)gridDim.x * 256 * 8;
  for (long i = i0; i < n; i += stride) {
    float4 a = *(const float4*)(in + i);
    float4 b = *(const float4*)(in + i + 4);
    union { __hip_bfloat16 h[8]; int4 v; } p;
    p.h[0] = __float2bfloat16(a.x); p.h[1] = __float2bfloat16(a.y);
    p.h[2] = __float2bfloat16(a.z); p.h[3] = __float2bfloat16(a.w);
    p.h[4] = __float2bfloat16(b.x); p.h[5] = __float2bfloat16(b.y);
    p.h[6] = __float2bfloat16(b.z); p.h[7] = __float2bfloat16(b.w);
    *(int4*)(out + i) = p.v;
  }
}

// ---------------------------------------------------------------- LayerNorm -> bf16
__global__ __launch_bounds__(256) void ln_kernel(const float* __restrict__ x,
                                                 const float* __restrict__ w,
                                                 const float* __restrict__ b,
                                                 __hip_bfloat16* __restrict__ out) {
  __shared__ float red[8];
  const int row = blockIdx.x;
  const int tid = threadIdx.x;
  const float* xr = x + (long)row * DMODEL;
  float4 v0 = ((const float4*)xr)[tid * 2];
  float4 v1 = ((const float4*)xr)[tid * 2 + 1];
  float s  = v0.x + v0.y + v0.z + v0.w + v1.x + v1.y + v1.z + v1.w;
  float ss = v0.x*v0.x + v0.y*v0.y + v0.z*v0.z + v0.w*v0.w
           + v1.x*v1.x + v1.y*v1.y + v1.z*v1.z + v1.w*v1.w;
  #pragma unroll
  for (int m = 1; m < 64; m <<= 1) { s += __shfl_xor(s, m, 64); ss += __shfl_xor(ss, m, 64); }
  if ((tid & 63) == 0) { red[tid >> 6] = s; red[4 + (tid >> 6)] = ss; }
  __syncthreads();
  s  = red[0] + red[1] + red[2] + red[3];
  ss = red[4] + red[5] + red[6] + red[7];
  const float mu = s * (1.0f / DMODEL);
  const float rs = rsqrtf(ss * (1.0f / DMODEL) - mu * mu + 1e-5f);
  float4 w0 = ((const float4*)w)[tid * 2], w1 = ((const float4*)w)[tid * 2 + 1];
  float4 b0 = ((const float4*)b)[tid * 2], b1 = ((const float4*)b)[tid * 2 + 1];
  union { __hip_bfloat16 h[8]; int4 v; } p;
  p.h[0] = __float2bfloat16((v0.x - mu) * rs * w0.x + b0.x);
  p.h[1] = __float2bfloat16((v0.y - mu) * rs * w0.y + b0.y);
  p.h[2] = __float2bfloat16((v0.z - mu) * rs * w0.z + b0.z);
  p.h[3] = __float2bfloat16((v0.w - mu) * rs * w0.w + b0.w);
  p.h[4] = __float2bfloat16((v1.x - mu) * rs * w1.x + b1.x);
  p.h[5] = __float2bfloat16((v1.y - mu) * rs * w1.y + b1.y);
  p.h[6] = __float2bfloat16((v1.z - mu) * rs * w1.z + b1.z);
  p.h[7] = __float2bfloat16((v1.w - mu) * rs * w1.w + b1.w);
  ((int4*)(out + (long)row * DMODEL))[tid] = p.v;
}

// ---------------------------------------------------------------- GEMM macros
#define VMBAR0() asm volatile("s_waitcnt vmcnt(0)\ns_barrier" ::: "memory")
#define LGK(N)   do { asm volatile("s_waitcnt lgkmcnt(" #N ")" ::: "memory"); \
                      __builtin_amdgcn_sched_barrier(0); } while (0)

#define RA_READ_A(DST, BB, MH) \
  _Pragma("unroll") \
  for (int m = 0; m < 4; ++m) { \
    int row = wr * 128 + (MH) * 64 + m * 16 + l15; \
    _Pragma("unroll") \
    for (int kk = 0; kk < 2; ++kk) \
      DST[m][kk] = *(const short8v*)((BB) + row * 128 + ((((kk << 2) | c16) ^ (row & 7)) << 4)); \
  }
#define RA_READ_B(DST, BB) \
  _Pragma("unroll") \
  for (int n = 0; n < 2; ++n) { \
    int row = wc * 32 + n * 16 + l15; \
    _Pragma("unroll") \
    for (int kk = 0; kk < 2; ++kk) \
      DST[n][kk] = *(const short8v*)((BB) + 32768 + row * 128 + ((((kk << 2) | c16) ^ (row & 7)) << 4)); \
  }
#define RA_MFMA(AF, BF, MH) \
  __builtin_amdgcn_s_setprio(1); \
  _Pragma("unroll") \
  for (int m = 0; m < 4; ++m) \
    _Pragma("unroll") \
    for (int n = 0; n < 2; ++n) \
      _Pragma("unroll") \
      for (int kk = 0; kk < 2; ++kk) \
        acc[(MH) * 4 + m][n] = __builtin_amdgcn_mfma_f32_16x16x32_bf16( \
            AF[m][kk], BF[n][kk], acc[(MH) * 4 + m][n], 0, 0, 0); \
  __builtin_amdgcn_s_setprio(0);

// ---------------------------------------------------------------- 256x128 free-run GEMM (all GEMMs)
// BM=256, BN=128, BK=64, 8 waves (2Mx4N), wave-tile 128x32, acc[8][2].
// FREE-RUN: ONE vmcnt(0)+barrier per K-tile (at buffer swap only). Within a
// tile waves run unsynchronized: staging writes target the other buffer and
// per-thread gload_lds dests are disjoint, so no intra-tile barrier is needed.
// Counted lgkmcnt (8) hides frag-read latency under MFMA; stage(t+2) issued
// right after the boundary barrier (lead ~1 tile >> HBM latency).
template <int MODE>
__global__ __launch_bounds__(512, 2) void gemm128fr(const __hip_bfloat16* __restrict__ A,
                                                    const __hip_bfloat16* __restrict__ B,
                                                    const float* __restrict__ bias,
                                                    const float* __restrict__ resid,
                                                    void* __restrict__ outp,
                                                    int N, long K) {
  __shared__ __align__(16) char lds[98304];   // 2 x (A 32KB | B 16KB)
  const int tid = threadIdx.x;
  const int lane = tid & 63, w = tid >> 6;
  const int wr = w >> 2, wc = w & 3;
  const int l15 = lane & 15, c16 = lane >> 4;
  // T1: bijective XCD remap (nwg % 8 == 0 for all our grids)
  const int gx = gridDim.x;
  const int nwg = gx * (int)gridDim.y;
  const int lin = (int)blockIdx.y * gx + (int)blockIdx.x;
  const int cpx = nwg >> 3;
  const int swz = (lin & 7) * cpx + (lin >> 3);
  const long m0 = (long)(swz / gx) * 256;
  const long n0 = (long)(swz % gx) * 128;
  const int NT = (int)(K >> 6);
  const int NI = NT >> 1;

  auto stA2 = [&](int t, int par) {           // par 0: quarters {0,2}; 1: {1,3}
    char* base = lds + (t & 1) * 49152;
    #pragma unroll
    for (int j = 0; j < 2; ++j) {
      int q = 2 * j + par;
      int row = q * 64 + (tid >> 3);
      long col = (long)t * 64 + (((tid & 7) ^ (row & 7)) << 3);
      async_ld16(A + (m0 + row) * K + col, base + q * 8192 + w * 1024);
    }
  };
  auto stB1 = [&](int t) {                    // full 128-row B tile (16KB)
    char* base = lds + (t & 1) * 49152 + 32768;
    #pragma unroll
    for (int j = 0; j < 2; ++j) {
      int row = j * 64 + (tid >> 3);
      long col = (long)t * 64 + (((tid & 7) ^ (row & 7)) << 3);
      async_ld16(B + (n0 + row) * K + col, base + j * 8192 + w * 1024);
    }
  };

  f32x4 acc[8][2] = {};
  short8v afA[4][2], afB[4][2], bfA[2][2];
  const char* b0 = lds;
  const char* b1 = lds + 49152;

  // prologue: tile0 staged+drained, tile1 in flight, tile0 mh0/B frags pre-read
  stB1(0); stA2(0, 0); stA2(0, 1);
  VMBAR0();
  stB1(1); stA2(1, 0); stA2(1, 1);
  RA_READ_A(afA, b0, 0); RA_READ_B(bfA, b0);

  for (int i = 0; i < NI; ++i) {
    // ---- tile 2i (buf0); stage(2i+1) in flight -> buf1
    RA_READ_A(afB, b0, 1);
    LGK(8);  RA_MFMA(afA, bfA, 0);
    LGK(0);  RA_MFMA(afB, bfA, 1);
    // boundary: tile 2i+1 landed; all waves done reading buf0
    VMBAR0();
    if (2 * i + 2 < NT) { stB1(2 * i + 2); stA2(2 * i + 2, 0); stA2(2 * i + 2, 1); }
    RA_READ_A(afA, b1, 0); RA_READ_B(bfA, b1);
    // ---- tile 2i+1 (buf1); stage(2i+2) in flight -> buf0
    RA_READ_A(afB, b1, 1);
    LGK(8);  RA_MFMA(afA, bfA, 0);
    LGK(0);  RA_MFMA(afB, bfA, 1);
    if (i + 1 < NI) {
      // boundary: tile 2i+2 landed; all waves done reading buf1
      VMBAR0();
      stB1(2 * i + 3); stA2(2 * i + 3, 0); stA2(2 * i + 3, 1);
      RA_READ_A(afA, b0, 0); RA_READ_B(bfA, b0);
    }
  }

  const int colq = l15;
  const int rowq = c16 * 4;
  #pragma unroll
  for (int n = 0; n < 2; ++n) {
    long col = n0 + wc * 32 + n * 16 + colq;
    float bi = bias[col];
    #pragma unroll
    for (int mi = 0; mi < 8; ++mi) {
      long row0 = m0 + wr * 128 + mi * 16 + rowq;
      #pragma unroll
      for (int j = 0; j < 4; ++j) {
        long idx = (row0 + j) * (long)N + col;
        float v = acc[mi][n][j] + bi;
        if (MODE == 0) {
          ((__hip_bfloat16*)outp)[idx] = __float2bfloat16(v);
        } else if (MODE == 1) {
          ((float*)outp)[idx] = v + resid[idx];
        } else {
          float g = 0.5f * v * (1.0f + erff(v * 0.70710678118654752f));
          ((__hip_bfloat16*)outp)[idx] = __float2bfloat16(g);
        }
      }
    }
  }
}

// ---------------------------------------------------------------- causal flash attention (R10-passing)
#define QBLK 128
#define KVB  64
#define VSTR 144                      // Vt row stride bytes (72 elems)
#define KBYT 16384                    // K buffer bytes
#define VBYT (DHEAD * VSTR)           // 18432
__global__ __launch_bounds__(256, 2) void attn_kernel(const __hip_bfloat16* __restrict__ qkv,
                                                      __hip_bfloat16* __restrict__ out) {
  __shared__ __align__(16) char smem[2 * KBYT + 2 * VBYT];
  const int tid = threadIdx.x, lane = tid & 63, wid = tid >> 6;
  const int l31 = lane & 31, hi = lane >> 5;
  const int bx = blockIdx.x;
  const int bh = blockIdx.y;
  const int bb = bh >> 4, h = bh & 15;
  const long rowbase = (long)bb * SEQ;
  const int qcol = h * DHEAD, kcol = DMODEL + h * DHEAD, vcol = 2 * DMODEL + h * DHEAD;

  const int kv0s = (tid >> 4) * 4;
  const int dh0s = (tid & 15) * 8;
  auto k_stage = [&](int t) {
    char* kb = smem + (t & 1) * KBYT;
    const long kvr = rowbase + (long)t * KVB;
    #pragma unroll
    for (int i = 0; i < 4; ++i) {
      int c = i * 256 + tid;
      int row = c >> 4, slot = c & 15;
      const void* src = qkv + (kvr + row) * TD + kcol + ((slot ^ (row & 7)) << 3);
      async_ld16(src, kb + i * 4096 + wid * 1024);
    }
  };
  auto v_load = [&](int t, int4* r) {
    const long kvr = rowbase + (long)t * KVB;
    #pragma unroll
    for (int i = 0; i < 4; ++i)
      r[i] = *(const int4*)(qkv + (kvr + kv0s + i) * TD + vcol + dh0s);
  };
  auto v_write = [&](int t, const int4* r) {
    char* vt = smem + 2 * KBYT + (t & 1) * VBYT;
    union { int4 v; unsigned short s[8]; } u0, u1, u2, u3;
    u0.v = r[0]; u1.v = r[1]; u2.v = r[2]; u3.v = r[3];
    #pragma unroll
    for (int dd = 0; dd < 8; ++dd) {
      int d = (dd + ((tid >> 1) & 7)) & 7;
      unsigned lo = (unsigned)u0.s[d] | ((unsigned)u1.s[d] << 16);
      unsigned hi2 = (unsigned)u2.s[d] | ((unsigned)u3.s[d] << 16);
      uint2 wv; wv.x = lo; wv.y = hi2;
      *(uint2*)(vt + (dh0s + d) * VSTR + kv0s * 2) = wv;
    }
  };

  #pragma unroll
  for (int mem = 0; mem < 2; ++mem) {
    const int qb = mem == 0 ? (15 - bx) : bx;   // long member first
    const int q0 = qb * QBLK;
    const int qw0 = q0 + wid * 32;

    short8v qf[8];
    {
      const __hip_bfloat16* qp = qkv + (rowbase + qw0 + l31) * TD + qcol + hi * 8;
      #pragma unroll
      for (int kc = 0; kc < 8; ++kc) qf[kc] = *(const short8v*)(qp + kc * 16);
    }

    f32x16 o[4] = {};
    float m_ = -1e30f, l_ = 0.0f;
    const int nt = (q0 + QBLK) / KVB;

    {
      int4 vr[4];
      v_load(0, vr);
      k_stage(0);
      v_write(0, vr);
    }
    __syncthreads();

    for (int t = 0; t < nt; ++t) {
      int4 vr[4];
      const bool more = (t + 1 < nt);
      if (more) { v_load(t + 1, vr); k_stage(t + 1); }

      const int kv0 = t * KVB;
      if (kv0 <= qw0 + 31) {
        const char* Kb = smem + (t & 1) * KBYT;
        f32x16 s0 = {}, s1 = {};
        #pragma unroll
        for (int kc = 0; kc < 8; ++kc) {
          const int colb = kc * 32 + hi * 16;
          const int r0 = l31, r1 = 32 + l31;
          short8v k0 = *(const short8v*)(Kb + r0 * 256 + (colb ^ ((r0 & 7) << 4)));
          short8v k1 = *(const short8v*)(Kb + r1 * 256 + (colb ^ ((r0 & 7) << 4)));
          s0 = __builtin_amdgcn_mfma_f32_32x32x16_bf16(k0, qf[kc], s0, 0, 0, 0);
          s1 = __builtin_amdgcn_mfma_f32_32x32x16_bf16(k1, qf[kc], s1, 0, 0, 0);
        }
        const float scale = 0.08838834764831845f;
        float sv[32];
        #pragma unroll
        for (int r = 0; r < 16; ++r) { sv[r] = s0[r] * scale; sv[16 + r] = s1[r] * scale; }
        const int qg = qw0 + l31;
        if (kv0 + KVB - 1 > qw0) {
          #pragma unroll
          for (int r = 0; r < 16; ++r) {
            int kvr_ = kv0 + (r & 3) + 8 * (r >> 2) + 4 * hi;
            if (kvr_ > qg)      sv[r]      = -1e30f;
            if (kvr_ + 32 > qg) sv[16 + r] = -1e30f;
          }
        }
        float pmax = sv[0];
        #pragma unroll
        for (int r = 1; r < 32; ++r) pmax = fmaxf(pmax, sv[r]);
        pmax = fmaxf(pmax, __shfl_xor(pmax, 32, 64));
        float mn = fmaxf(m_, pmax);
        float alpha = __expf(m_ - mn);
        m_ = mn;
        l_ *= alpha;
        #pragma unroll
        for (int d = 0; d < 4; ++d)
          #pragma unroll
          for (int r = 0; r < 16; ++r) o[d][r] *= alpha;
        float rsum = 0.0f;
        #pragma unroll
        for (int r = 0; r < 32; ++r) { sv[r] = __expf(sv[r] - m_); rsum += sv[r]; }
        l_ += rsum + __shfl_xor(rsum, 32, 64);
        int pa_[4][4];
        #pragma unroll
        for (int kc = 0; kc < 4; ++kc) {
          int ba = 16 * (kc >> 1) + 8 * (kc & 1);
          unsigned wA0 = pk2(sv[ba + 0], sv[ba + 1]);
          unsigned wA1 = pk2(sv[ba + 2], sv[ba + 3]);
          unsigned wB0 = pk2(sv[ba + 4], sv[ba + 5]);
          unsigned wB1 = pk2(sv[ba + 6], sv[ba + 7]);
          unsigned z0 = (unsigned)__shfl_xor((int)(hi ? wA0 : wB0), 32, 64);
          unsigned z1 = (unsigned)__shfl_xor((int)(hi ? wA1 : wB1), 32, 64);
          pa_[kc][0] = hi ? (int)z0 : (int)wA0;
          pa_[kc][1] = hi ? (int)z1 : (int)wA1;
          pa_[kc][2] = hi ? (int)wB0 : (int)z0;
          pa_[kc][3] = hi ? (int)wB1 : (int)z1;
        }
        const char* Vt = smem + 2 * KBYT + (t & 1) * VBYT;
        #pragma unroll
        for (int dht = 0; dht < 4; ++dht) {
          const int dh = dht * 32 + l31;
          short8v vf[4];
          #pragma unroll
          for (int kc = 0; kc < 4; ++kc)
            vf[kc] = *(const short8v*)(Vt + dh * VSTR + kc * 32 + hi * 16);
          #pragma unroll
          for (int kc = 0; kc < 4; ++kc) {
            union { int i[4]; short8v v; } bv;
            bv.i[0] = pa_[kc][0]; bv.i[1] = pa_[kc][1];
            bv.i[2] = pa_[kc][2]; bv.i[3] = pa_[kc][3];
            o[dht] = __builtin_amdgcn_mfma_f32_32x32x16_bf16(vf[kc], bv.v, o[dht], 0, 0, 0);
          }
        }
      }
      if (more) v_write(t + 1, vr);
      __syncthreads();
    }

    const float linv = 1.0f / l_;
    const long orow = (rowbase + qw0 + l31) * DMODEL + h * DHEAD;
    #pragma unroll
    for (int dht = 0; dht < 4; ++dht)
      #pragma unroll
      for (int rg = 0; rg < 4; ++rg) {
        union { __hip_bfloat16 hh[4]; uint2 u; } pk;
        #pragma unroll
        for (int i = 0; i < 4; ++i) pk.hh[i] = __float2bfloat16(o[dht][rg * 4 + i] * linv);
        *(uint2*)(out + orow + dht * 32 + 8 * rg + 4 * hi) = pk.u;
      }
  }
}

// ---------------------------------------------------------------- launch
extern "C" void kernel_launch(void* const* d_in, const int* in_sizes, int n_in,
                              void* d_out, int out_size, void* d_ws, size_t ws_size,
                              hipStream_t stream) {
  const float* hidden  = (const float*)d_in[0];
  const float* ln1w    = (const float*)d_in[1];
  const float* ln1b    = (const float*)d_in[2];
  const float* qkvw    = (const float*)d_in[3];
  const float* qkvb    = (const float*)d_in[4];
  const float* densew  = (const float*)d_in[5];
  const float* denseb  = (const float*)d_in[6];
  const float* ln2w    = (const float*)d_in[7];
  const float* ln2b    = (const float*)d_in[8];
  const float* fc1w    = (const float*)d_in[9];
  const float* fc1b    = (const float*)d_in[10];
  const float* fc2w    = (const float*)d_in[11];
  const float* fc2b    = (const float*)d_in[12];

  char* ws = (char*)d_ws;
  size_t off = 0;
  auto alloc = [&](size_t bytes) { char* p = ws + off; off += (bytes + 255) & ~(size_t)255; return p; };
  __hip_bfloat16* xbf    = (__hip_bfloat16*)alloc((size_t)TOK * DMODEL * 2);
  __hip_bfloat16* wqkv   = (__hip_bfloat16*)alloc((size_t)TD * DMODEL * 2);
  __hip_bfloat16* wdense = (__hip_bfloat16*)alloc((size_t)DMODEL * DMODEL * 2);
  __hip_bfloat16* wfc1   = (__hip_bfloat16*)alloc((size_t)FFDIM * DMODEL * 2);
  __hip_bfloat16* wfc2   = (__hip_bfloat16*)alloc((size_t)DMODEL * FFDIM * 2);
  __hip_bfloat16* big    = (__hip_bfloat16*)alloc((size_t)TOK * FFDIM * 2);
  float*          x2     = (float*)alloc((size_t)TOK * DMODEL * 4);
  __hip_bfloat16* qkvbuf  = big;
  __hip_bfloat16* attnout = big + (size_t)TOK * TD;
  __hip_bfloat16* gelubuf = big;

  f2bf_kernel<<<1024, 256, 0, stream>>>(qkvw,   wqkv,   (long)TD * DMODEL);
  f2bf_kernel<<<1024, 256, 0, stream>>>(densew, wdense, (long)DMODEL * DMODEL);
  f2bf_kernel<<<1024, 256, 0, stream>>>(fc1w,   wfc1,   (long)FFDIM * DMODEL);
  f2bf_kernel<<<1024, 256, 0, stream>>>(fc2w,   wfc2,   (long)DMODEL * FFDIM);

  ln_kernel<<<TOK, 256, 0, stream>>>(hidden, ln1w, ln1b, xbf);
  gemm128fr<0><<<dim3(TD / 128, TOK / 256), 512, 0, stream>>>(xbf, wqkv, qkvb, nullptr, qkvbuf, TD, DMODEL);
  attn_kernel<<<dim3(8, 2 * NHEAD), 256, 0, stream>>>(qkvbuf, attnout);
  gemm128fr<1><<<dim3(DMODEL / 128, TOK / 256), 512, 0, stream>>>(attnout, wdense, denseb, hidden, x2, DMODEL, DMODEL);
  ln_kernel<<<TOK, 256, 0, stream>>>(x2, ln2w, ln2b, xbf);
  gemm128fr<2><<<dim3(FFDIM / 128, TOK / 256), 512, 0, stream>>>(xbf, wfc1, fc1b, nullptr, gelubuf, FFDIM, DMODEL);
  gemm128fr<1><<<dim3(DMODEL / 128, TOK / 256), 512, 0, stream>>>(gelubuf, wfc2, fc2b, x2, (float*)d_out, DMODEL, FFDIM);
}

// Round 13
// 671.810 us; speedup vs baseline: 1.0245x; 1.0245x over previous
//
#include <hip/hip_runtime.h>
#include <hip/hip_bf16.h>

#define SEQ    2048
#define DMODEL 2048
#define NHEAD  16
#define DHEAD  128
#define TOK    4096   // B*S
#define TD     6144   // 3*D
#define FFDIM  8192

typedef __attribute__((ext_vector_type(4)))  float f32x4;
typedef __attribute__((ext_vector_type(16))) float f32x16;
typedef __attribute__((ext_vector_type(8)))  short short8v;

__device__ __forceinline__ void async_ld16(const void* src, void* lds) {
  __builtin_amdgcn_global_load_lds((const __attribute__((address_space(1))) void*)src,
                                   (__attribute__((address_space(3))) void*)lds, 16, 0, 0);
}

__device__ __forceinline__ unsigned pk2(float a, float b) {
  union { __hip_bfloat16 h[2]; unsigned u; } p;
  p.h[0] = __float2bfloat16(a);
  p.h[1] = __float2bfloat16(b);
  return p.u;
}

// ---------------------------------------------------------------- fp32 -> bf16
__global__ __launch_bounds__(256) void f2bf_kernel(const float* __restrict__ in,
                                                   __hip_bfloat16* __restrict__ out, long n) {
  long i0 = ((long)blockIdx.x * 256 + threadIdx.x) * 8;
  long stride = (long)gridDim.x * 256 * 8;
  for (long i = i0; i < n; i += stride) {
    float4 a = *(const float4*)(in + i);
    float4 b = *(const float4*)(in + i + 4);
    union { __hip_bfloat16 h[8]; int4 v; } p;
    p.h[0] = __float2bfloat16(a.x); p.h[1] = __float2bfloat16(a.y);
    p.h[2] = __float2bfloat16(a.z); p.h[3] = __float2bfloat16(a.w);
    p.h[4] = __float2bfloat16(b.x); p.h[5] = __float2bfloat16(b.y);
    p.h[6] = __float2bfloat16(b.z); p.h[7] = __float2bfloat16(b.w);
    *(int4*)(out + i) = p.v;
  }
}

// ---------------------------------------------------------------- LayerNorm -> bf16
__global__ __launch_bounds__(256) void ln_kernel(const float* __restrict__ x,
                                                 const float* __restrict__ w,
                                                 const float* __restrict__ b,
                                                 __hip_bfloat16* __restrict__ out) {
  __shared__ float red[8];
  const int row = blockIdx.x;
  const int tid = threadIdx.x;
  const float* xr = x + (long)row * DMODEL;
  float4 v0 = ((const float4*)xr)[tid * 2];
  float4 v1 = ((const float4*)xr)[tid * 2 + 1];
  float s  = v0.x + v0.y + v0.z + v0.w + v1.x + v1.y + v1.z + v1.w;
  float ss = v0.x*v0.x + v0.y*v0.y + v0.z*v0.z + v0.w*v0.w
           + v1.x*v1.x + v1.y*v1.y + v1.z*v1.z + v1.w*v1.w;
  #pragma unroll
  for (int m = 1; m < 64; m <<= 1) { s += __shfl_xor(s, m, 64); ss += __shfl_xor(ss, m, 64); }
  if ((tid & 63) == 0) { red[tid >> 6] = s; red[4 + (tid >> 6)] = ss; }
  __syncthreads();
  s  = red[0] + red[1] + red[2] + red[3];
  ss = red[4] + red[5] + red[6] + red[7];
  const float mu = s * (1.0f / DMODEL);
  const float rs = rsqrtf(ss * (1.0f / DMODEL) - mu * mu + 1e-5f);
  float4 w0 = ((const float4*)w)[tid * 2], w1 = ((const float4*)w)[tid * 2 + 1];
  float4 b0 = ((const float4*)b)[tid * 2], b1 = ((const float4*)b)[tid * 2 + 1];
  union { __hip_bfloat16 h[8]; int4 v; } p;
  p.h[0] = __float2bfloat16((v0.x - mu) * rs * w0.x + b0.x);
  p.h[1] = __float2bfloat16((v0.y - mu) * rs * w0.y + b0.y);
  p.h[2] = __float2bfloat16((v0.z - mu) * rs * w0.z + b0.z);
  p.h[3] = __float2bfloat16((v0.w - mu) * rs * w0.w + b0.w);
  p.h[4] = __float2bfloat16((v1.x - mu) * rs * w1.x + b1.x);
  p.h[5] = __float2bfloat16((v1.y - mu) * rs * w1.y + b1.y);
  p.h[6] = __float2bfloat16((v1.z - mu) * rs * w1.z + b1.z);
  p.h[7] = __float2bfloat16((v1.w - mu) * rs * w1.w + b1.w);
  ((int4*)(out + (long)row * DMODEL))[tid] = p.v;
}

// ---------------------------------------------------------------- shared macros
#define VMBAR0() asm volatile("s_waitcnt vmcnt(0)\ns_barrier" ::: "memory")
#define VMBAR(N) asm volatile("s_waitcnt vmcnt(" #N ")\ns_barrier" ::: "memory")
#define LGK(N)   do { asm volatile("s_waitcnt lgkmcnt(" #N ")" ::: "memory"); \
                      __builtin_amdgcn_sched_barrier(0); } while (0)

// ---------------------------------------------------------------- 256x256 read-ahead GEMM (QKV/FC1/FC2-split)
// BM=256, BN=256, BK=64, 8 waves (2Mx4N), wave-tile 128x64, acc[8][4].
// Per K-tile: stage 8 gloads early; reads af(mh0)+bf(8); counted LGK gates;
// 2 barriers/tile (mid plain + boundary vmcnt(0)). Geometry gives 2.67 MFMA
// per ds_read_b128 (vs 1.6 at BN=128) -> LDS-BW ceiling ~80% not 48%.
// MODE 0: bf16 = acc+bias ; 2: bf16 = gelu(acc+bias) ; 3: fp32 partial (split-K, no bias)
#define R256_READ_A(BB, MH) \
  _Pragma("unroll") \
  for (int m = 0; m < 4; ++m) { \
    int row = wr * 128 + (MH) * 64 + m * 16 + l15; \
    _Pragma("unroll") \
    for (int kk = 0; kk < 2; ++kk) \
      af[m][kk] = *(const short8v*)((BB) + row * 128 + ((((kk << 2) | c16) ^ (row & 7)) << 4)); \
  }
#define R256_READ_B(NB) \
  _Pragma("unroll") \
  for (int n = 0; n < 2; ++n) { \
    int row = wc * 64 + ((NB) + n) * 16 + l15; \
    _Pragma("unroll") \
    for (int kk = 0; kk < 2; ++kk) \
      bf[(NB) + n][kk] = *(const short8v*)(bt + 32768 + row * 128 + ((((kk << 2) | c16) ^ (row & 7)) << 4)); \
  }
#define R256_MFMA(MH, NB) \
  __builtin_amdgcn_s_setprio(1); \
  _Pragma("unroll") \
  for (int m = 0; m < 4; ++m) \
    _Pragma("unroll") \
    for (int n = 0; n < 2; ++n) \
      _Pragma("unroll") \
      for (int kk = 0; kk < 2; ++kk) \
        acc[(MH) * 4 + m][(NB) + n] = __builtin_amdgcn_mfma_f32_16x16x32_bf16( \
            af[m][kk], bf[(NB) + n][kk], acc[(MH) * 4 + m][(NB) + n], 0, 0, 0); \
  __builtin_amdgcn_s_setprio(0);

template <int MODE>
__global__ __launch_bounds__(512, 2) void gemm256ra(const __hip_bfloat16* __restrict__ A,
                                                    const __hip_bfloat16* __restrict__ B,
                                                    const float* __restrict__ bias,
                                                    float* __restrict__ pbuf,
                                                    void* __restrict__ outp,
                                                    int N, long Ksub, long ldk, long pstride) {
  __shared__ __align__(16) char lds[131072];   // 2 x (A 32KB | B 32KB)
  const int tid = threadIdx.x;
  const int lane = tid & 63, w = tid >> 6;
  const int wr = w >> 2, wc = w & 3;
  const int l15 = lane & 15, c16 = lane >> 4;
  // T1: bijective XCD remap per z-slice (nwg % 8 == 0 for all our grids)
  const int gx = gridDim.x;
  const int nwg = gx * (int)gridDim.y;
  const int lin = (int)blockIdx.y * gx + (int)blockIdx.x;
  const int cpx = nwg >> 3;
  const int swz = (lin & 7) * cpx + (lin >> 3);
  const long m0 = (long)(swz / gx) * 256;
  const long n0 = (long)(swz % gx) * 256;
  const long koff = (long)blockIdx.z * Ksub;
  const int NT = (int)(Ksub >> 6);

  auto stA4 = [&](int t) {                    // A tile 32KB: 4 quarters
    char* base = lds + (t & 1) * 65536;
    #pragma unroll
    for (int j = 0; j < 4; ++j) {
      int row = j * 64 + (tid >> 3);
      long col = (long)t * 64 + (((tid & 7) ^ (row & 7)) << 3);
      async_ld16(A + (m0 + row) * ldk + koff + col, base + j * 8192 + w * 1024);
    }
  };
  auto stB4 = [&](int t) {                    // B tile 32KB: 4 quarters
    char* base = lds + (t & 1) * 65536 + 32768;
    #pragma unroll
    for (int j = 0; j < 4; ++j) {
      int row = j * 64 + (tid >> 3);
      long col = (long)t * 64 + (((tid & 7) ^ (row & 7)) << 3);
      async_ld16(B + (n0 + row) * ldk + koff + col, base + j * 8192 + w * 1024);
    }
  };

  f32x4 acc[8][4] = {};
  short8v af[4][2], bf[4][2];

  // prologue: stage tile 0 (8 loads), drain
  stA4(0); stB4(0);
  VMBAR0();

  for (int t = 0; t < NT; ++t) {
    const char* bt = lds + (t & 1) * 65536;
    const bool more = (t + 1 < NT);
    // issue next tile's staging early (other buffer; its readers passed the
    // boundary barrier ending tile t-1, which precedes this point)
    if (more) stA4(t + 1);
    R256_READ_A(bt, 0);        // 8 ds (af = mh0)
    R256_READ_B(0);            // 4 ds (bf01)
    R256_READ_B(2);            // 4 ds (bf23)
    if (more) stB4(t + 1);
    LGK(4);                    // af + bf01 landed (bf23 outstanding)
    R256_MFMA(0, 0);           // 16 MFMA: mh0 x b01
    LGK(0);                    // bf23 landed
    R256_MFMA(0, 2);           // 16 MFMA: mh0 x b23
    R256_READ_A(bt, 1);        // 8 ds (af = mh1; regs free after mh0 MFMAs issued)
    __builtin_amdgcn_s_barrier();   // mid-tile wave alignment
    LGK(0);                    // af(mh1) landed
    R256_MFMA(1, 0);           // 16 MFMA: mh1 x b01
    R256_MFMA(1, 2);           // 16 MFMA: mh1 x b23
    VMBAR0();                  // tile t+1 landed; all waves done reading buf t
  }

  const int colq = l15;
  const int rowq = c16 * 4;
  #pragma unroll
  for (int n = 0; n < 4; ++n) {
    long col = n0 + wc * 64 + n * 16 + colq;
    float bi = (MODE == 3) ? 0.0f : bias[col];
    #pragma unroll
    for (int mi = 0; mi < 8; ++mi) {
      long row0 = m0 + wr * 128 + mi * 16 + rowq;
      #pragma unroll
      for (int j = 0; j < 4; ++j) {
        long idx = (row0 + j) * (long)N + col;
        float v = acc[mi][n][j] + bi;
        if (MODE == 0) {
          ((__hip_bfloat16*)outp)[idx] = __float2bfloat16(v);
        } else if (MODE == 2) {
          float g = 0.5f * v * (1.0f + erff(v * 0.70710678118654752f));
          ((__hip_bfloat16*)outp)[idx] = __float2bfloat16(g);
        } else {
          pbuf[(long)blockIdx.z * pstride + idx] = v;
        }
      }
    }
  }
}

// ---------------------------------------------------------------- split-K reduce: out = p0+p1+resid+bias
__global__ __launch_bounds__(256) void addred_kernel(const float* __restrict__ p0,
                                                     const float* __restrict__ p1,
                                                     const float* __restrict__ resid,
                                                     const float* __restrict__ bias,
                                                     float* __restrict__ out) {
  long i = ((long)blockIdx.x * 256 + threadIdx.x) * 4;
  float4 a = *(const float4*)(p0 + i);
  float4 b = *(const float4*)(p1 + i);
  float4 r = *(const float4*)(resid + i);
  float4 bi = *(const float4*)(bias + (i & (DMODEL - 1)));
  float4 o;
  o.x = a.x + b.x + r.x + bi.x;
  o.y = a.y + b.y + r.y + bi.y;
  o.z = a.z + b.z + r.z + bi.z;
  o.w = a.w + b.w + r.w + bi.w;
  *(float4*)(out + i) = o;
}

// ---------------------------------------------------------------- 256x128 read-ahead GEMM (dense; R11-passing)
#define RA_READ_A(DST, BB, MH) \
  _Pragma("unroll") \
  for (int m = 0; m < 4; ++m) { \
    int row = wr * 128 + (MH) * 64 + m * 16 + l15; \
    _Pragma("unroll") \
    for (int kk = 0; kk < 2; ++kk) \
      DST[m][kk] = *(const short8v*)((BB) + row * 128 + ((((kk << 2) | c16) ^ (row & 7)) << 4)); \
  }
#define RA_READ_B(DST, BB) \
  _Pragma("unroll") \
  for (int n = 0; n < 2; ++n) { \
    int row = wc * 32 + n * 16 + l15; \
    _Pragma("unroll") \
    for (int kk = 0; kk < 2; ++kk) \
      DST[n][kk] = *(const short8v*)((BB) + 32768 + row * 128 + ((((kk << 2) | c16) ^ (row & 7)) << 4)); \
  }
#define RA_MFMA(AF, BF, MH) \
  __builtin_amdgcn_s_setprio(1); \
  _Pragma("unroll") \
  for (int m = 0; m < 4; ++m) \
    _Pragma("unroll") \
    for (int n = 0; n < 2; ++n) \
      _Pragma("unroll") \
      for (int kk = 0; kk < 2; ++kk) \
        acc[(MH) * 4 + m][n] = __builtin_amdgcn_mfma_f32_16x16x32_bf16( \
            AF[m][kk], BF[n][kk], acc[(MH) * 4 + m][n], 0, 0, 0); \
  __builtin_amdgcn_s_setprio(0);

template <int MODE>
__global__ __launch_bounds__(512, 2) void gemm128ra(const __hip_bfloat16* __restrict__ A,
                                                    const __hip_bfloat16* __restrict__ B,
                                                    const float* __restrict__ bias,
                                                    const float* __restrict__ resid,
                                                    void* __restrict__ outp,
                                                    int N, long K) {
  __shared__ __align__(16) char lds[98304];   // 2 x (A 32KB | B 16KB)
  const int tid = threadIdx.x;
  const int lane = tid & 63, w = tid >> 6;
  const int wr = w >> 2, wc = w & 3;
  const int l15 = lane & 15, c16 = lane >> 4;
  const int gx = gridDim.x;
  const int nwg = gx * (int)gridDim.y;
  const int lin = (int)blockIdx.y * gx + (int)blockIdx.x;
  const int cpx = nwg >> 3;
  const int swz = (lin & 7) * cpx + (lin >> 3);
  const long m0 = (long)(swz / gx) * 256;
  const long n0 = (long)(swz % gx) * 128;
  const int NT = (int)(K >> 6);
  const int NI = NT >> 1;

  auto stA2 = [&](int t, int par) {
    char* base = lds + (t & 1) * 49152;
    #pragma unroll
    for (int j = 0; j < 2; ++j) {
      int q = 2 * j + par;
      int row = q * 64 + (tid >> 3);
      long col = (long)t * 64 + (((tid & 7) ^ (row & 7)) << 3);
      async_ld16(A + (m0 + row) * K + col, base + q * 8192 + w * 1024);
    }
  };
  auto stB1 = [&](int t) {
    char* base = lds + (t & 1) * 49152 + 32768;
    #pragma unroll
    for (int j = 0; j < 2; ++j) {
      int row = j * 64 + (tid >> 3);
      long col = (long)t * 64 + (((tid & 7) ^ (row & 7)) << 3);
      async_ld16(B + (n0 + row) * K + col, base + j * 8192 + w * 1024);
    }
  };

  f32x4 acc[8][2] = {};
  short8v afA[4][2], afB[4][2], bfA[2][2];
  const char* b0 = lds;
  const char* b1 = lds + 49152;

  stB1(0); stA2(0, 0); stA2(0, 1);
  stB1(1); stA2(1, 0);
  VMBAR(4);
  RA_READ_A(afA, b0, 0);

  for (int i = 0; i < NI; ++i) {
    const bool last = (i == NI - 1);
    const int c = 2 * i + 1, e = 2 * i + 2, g = 2 * i + 3;

    // ---- P1
    RA_READ_B(bfA, b0);
    RA_READ_A(afB, b0, 1);
    stA2(c, 1);
    LGK(8);
    RA_MFMA(afA, bfA, 0);
    // ---- P2
    VMBAR(2);
    RA_READ_A(afA, b1, 0);
    if (!last) { stB1(e); stA2(e, 0); }
    LGK(8);
    RA_MFMA(afB, bfA, 1);
    // ---- P3
    if (!last) { VMBAR(4); } else { VMBAR(0); }
    RA_READ_B(bfA, b1);
    RA_READ_A(afB, b1, 1);
    if (!last) stA2(e, 1);
    LGK(8);
    RA_MFMA(afA, bfA, 0);
    // ---- P4
    if (!last) {
      VMBAR(2);
      RA_READ_A(afA, b0, 0);
      stB1(g); stA2(g, 0);
      LGK(8);
    } else {
      LGK(0);
    }
    RA_MFMA(afB, bfA, 1);
  }

  const int colq = l15;
  const int rowq = c16 * 4;
  #pragma unroll
  for (int n = 0; n < 2; ++n) {
    long col = n0 + wc * 32 + n * 16 + colq;
    float bi = bias[col];
    #pragma unroll
    for (int mi = 0; mi < 8; ++mi) {
      long row0 = m0 + wr * 128 + mi * 16 + rowq;
      #pragma unroll
      for (int j = 0; j < 4; ++j) {
        long idx = (row0 + j) * (long)N + col;
        float v = acc[mi][n][j] + bi;
        if (MODE == 0) {
          ((__hip_bfloat16*)outp)[idx] = __float2bfloat16(v);
        } else if (MODE == 1) {
          ((float*)outp)[idx] = v + resid[idx];
        } else {
          float g2 = 0.5f * v * (1.0f + erff(v * 0.70710678118654752f));
          ((__hip_bfloat16*)outp)[idx] = __float2bfloat16(g2);
        }
      }
    }
  }
}

// ---------------------------------------------------------------- causal flash attention (R10-passing)
#define QBLK 128
#define KVB  64
#define VSTR 144
#define KBYT 16384
#define VBYT (DHEAD * VSTR)
__global__ __launch_bounds__(256, 2) void attn_kernel(const __hip_bfloat16* __restrict__ qkv,
                                                      __hip_bfloat16* __restrict__ out) {
  __shared__ __align__(16) char smem[2 * KBYT + 2 * VBYT];
  const int tid = threadIdx.x, lane = tid & 63, wid = tid >> 6;
  const int l31 = lane & 31, hi = lane >> 5;
  const int bx = blockIdx.x;
  const int bh = blockIdx.y;
  const int bb = bh >> 4, h = bh & 15;
  const long rowbase = (long)bb * SEQ;
  const int qcol = h * DHEAD, kcol = DMODEL + h * DHEAD, vcol = 2 * DMODEL + h * DHEAD;

  const int kv0s = (tid >> 4) * 4;
  const int dh0s = (tid & 15) * 8;
  auto k_stage = [&](int t) {
    char* kb = smem + (t & 1) * KBYT;
    const long kvr = rowbase + (long)t * KVB;
    #pragma unroll
    for (int i = 0; i < 4; ++i) {
      int c = i * 256 + tid;
      int row = c >> 4, slot = c & 15;
      const void* src = qkv + (kvr + row) * TD + kcol + ((slot ^ (row & 7)) << 3);
      async_ld16(src, kb + i * 4096 + wid * 1024);
    }
  };
  auto v_load = [&](int t, int4* r) {
    const long kvr = rowbase + (long)t * KVB;
    #pragma unroll
    for (int i = 0; i < 4; ++i)
      r[i] = *(const int4*)(qkv + (kvr + kv0s + i) * TD + vcol + dh0s);
  };
  auto v_write = [&](int t, const int4* r) {
    char* vt = smem + 2 * KBYT + (t & 1) * VBYT;
    union { int4 v; unsigned short s[8]; } u0, u1, u2, u3;
    u0.v = r[0]; u1.v = r[1]; u2.v = r[2]; u3.v = r[3];
    #pragma unroll
    for (int dd = 0; dd < 8; ++dd) {
      int d = (dd + ((tid >> 1) & 7)) & 7;
      unsigned lo = (unsigned)u0.s[d] | ((unsigned)u1.s[d] << 16);
      unsigned hi2 = (unsigned)u2.s[d] | ((unsigned)u3.s[d] << 16);
      uint2 wv; wv.x = lo; wv.y = hi2;
      *(uint2*)(vt + (dh0s + d) * VSTR + kv0s * 2) = wv;
    }
  };

  #pragma unroll
  for (int mem = 0; mem < 2; ++mem) {
    const int qb = mem == 0 ? (15 - bx) : bx;
    const int q0 = qb * QBLK;
    const int qw0 = q0 + wid * 32;

    short8v qf[8];
    {
      const __hip_bfloat16* qp = qkv + (rowbase + qw0 + l31) * TD + qcol + hi * 8;
      #pragma unroll
      for (int kc = 0; kc < 8; ++kc) qf[kc] = *(const short8v*)(qp + kc * 16);
    }

    f32x16 o[4] = {};
    float m_ = -1e30f, l_ = 0.0f;
    const int nt = (q0 + QBLK) / KVB;

    {
      int4 vr[4];
      v_load(0, vr);
      k_stage(0);
      v_write(0, vr);
    }
    __syncthreads();

    for (int t = 0; t < nt; ++t) {
      int4 vr[4];
      const bool more = (t + 1 < nt);
      if (more) { v_load(t + 1, vr); k_stage(t + 1); }

      const int kv0 = t * KVB;
      if (kv0 <= qw0 + 31) {
        const char* Kb = smem + (t & 1) * KBYT;
        f32x16 s0 = {}, s1 = {};
        #pragma unroll
        for (int kc = 0; kc < 8; ++kc) {
          const int colb = kc * 32 + hi * 16;
          const int r0 = l31, r1 = 32 + l31;
          short8v k0 = *(const short8v*)(Kb + r0 * 256 + (colb ^ ((r0 & 7) << 4)));
          short8v k1 = *(const short8v*)(Kb + r1 * 256 + (colb ^ ((r0 & 7) << 4)));
          s0 = __builtin_amdgcn_mfma_f32_32x32x16_bf16(k0, qf[kc], s0, 0, 0, 0);
          s1 = __builtin_amdgcn_mfma_f32_32x32x16_bf16(k1, qf[kc], s1, 0, 0, 0);
        }
        const float scale = 0.08838834764831845f;
        float sv[32];
        #pragma unroll
        for (int r = 0; r < 16; ++r) { sv[r] = s0[r] * scale; sv[16 + r] = s1[r] * scale; }
        const int qg = qw0 + l31;
        if (kv0 + KVB - 1 > qw0) {
          #pragma unroll
          for (int r = 0; r < 16; ++r) {
            int kvr_ = kv0 + (r & 3) + 8 * (r >> 2) + 4 * hi;
            if (kvr_ > qg)      sv[r]      = -1e30f;
            if (kvr_ + 32 > qg) sv[16 + r] = -1e30f;
          }
        }
        float pmax = sv[0];
        #pragma unroll
        for (int r = 1; r < 32; ++r) pmax = fmaxf(pmax, sv[r]);
        pmax = fmaxf(pmax, __shfl_xor(pmax, 32, 64));
        float mn = fmaxf(m_, pmax);
        float alpha = __expf(m_ - mn);
        m_ = mn;
        l_ *= alpha;
        #pragma unroll
        for (int d = 0; d < 4; ++d)
          #pragma unroll
          for (int r = 0; r < 16; ++r) o[d][r] *= alpha;
        float rsum = 0.0f;
        #pragma unroll
        for (int r = 0; r < 32; ++r) { sv[r] = __expf(sv[r] - m_); rsum += sv[r]; }
        l_ += rsum + __shfl_xor(rsum, 32, 64);
        int pa_[4][4];
        #pragma unroll
        for (int kc = 0; kc < 4; ++kc) {
          int ba = 16 * (kc >> 1) + 8 * (kc & 1);
          unsigned wA0 = pk2(sv[ba + 0], sv[ba + 1]);
          unsigned wA1 = pk2(sv[ba + 2], sv[ba + 3]);
          unsigned wB0 = pk2(sv[ba + 4], sv[ba + 5]);
          unsigned wB1 = pk2(sv[ba + 6], sv[ba + 7]);
          unsigned z0 = (unsigned)__shfl_xor((int)(hi ? wA0 : wB0), 32, 64);
          unsigned z1 = (unsigned)__shfl_xor((int)(hi ? wA1 : wB1), 32, 64);
          pa_[kc][0] = hi ? (int)z0 : (int)wA0;
          pa_[kc][1] = hi ? (int)z1 : (int)wA1;
          pa_[kc][2] = hi ? (int)wB0 : (int)z0;
          pa_[kc][3] = hi ? (int)wB1 : (int)z1;
        }
        const char* Vt = smem + 2 * KBYT + (t & 1) * VBYT;
        #pragma unroll
        for (int dht = 0; dht < 4; ++dht) {
          const int dh = dht * 32 + l31;
          short8v vf[4];
          #pragma unroll
          for (int kc = 0; kc < 4; ++kc)
            vf[kc] = *(const short8v*)(Vt + dh * VSTR + kc * 32 + hi * 16);
          #pragma unroll
          for (int kc = 0; kc < 4; ++kc) {
            union { int i[4]; short8v v; } bv;
            bv.i[0] = pa_[kc][0]; bv.i[1] = pa_[kc][1];
            bv.i[2] = pa_[kc][2]; bv.i[3] = pa_[kc][3];
            o[dht] = __builtin_amdgcn_mfma_f32_32x32x16_bf16(vf[kc], bv.v, o[dht], 0, 0, 0);
          }
        }
      }
      if (more) v_write(t + 1, vr);
      __syncthreads();
    }

    const float linv = 1.0f / l_;
    const long orow = (rowbase + qw0 + l31) * DMODEL + h * DHEAD;
    #pragma unroll
    for (int dht = 0; dht < 4; ++dht)
      #pragma unroll
      for (int rg = 0; rg < 4; ++rg) {
        union { __hip_bfloat16 hh[4]; uint2 u; } pk;
        #pragma unroll
        for (int i = 0; i < 4; ++i) pk.hh[i] = __float2bfloat16(o[dht][rg * 4 + i] * linv);
        *(uint2*)(out + orow + dht * 32 + 8 * rg + 4 * hi) = pk.u;
      }
  }
}

// ---------------------------------------------------------------- launch
extern "C" void kernel_launch(void* const* d_in, const int* in_sizes, int n_in,
                              void* d_out, int out_size, void* d_ws, size_t ws_size,
                              hipStream_t stream) {
  const float* hidden  = (const float*)d_in[0];
  const float* ln1w    = (const float*)d_in[1];
  const float* ln1b    = (const float*)d_in[2];
  const float* qkvw    = (const float*)d_in[3];
  const float* qkvb    = (const float*)d_in[4];
  const float* densew  = (const float*)d_in[5];
  const float* denseb  = (const float*)d_in[6];
  const float* ln2w    = (const float*)d_in[7];
  const float* ln2b    = (const float*)d_in[8];
  const float* fc1w    = (const float*)d_in[9];
  const float* fc1b    = (const float*)d_in[10];
  const float* fc2w    = (const float*)d_in[11];
  const float* fc2b    = (const float*)d_in[12];

  char* ws = (char*)d_ws;
  size_t off = 0;
  auto alloc = [&](size_t bytes) { char* p = ws + off; off += (bytes + 255) & ~(size_t)255; return p; };
  __hip_bfloat16* xbf    = (__hip_bfloat16*)alloc((size_t)TOK * DMODEL * 2);   // 16MB
  __hip_bfloat16* wqkv   = (__hip_bfloat16*)alloc((size_t)TD * DMODEL * 2);    // 24MB
  __hip_bfloat16* wdense = (__hip_bfloat16*)alloc((size_t)DMODEL * DMODEL * 2);// 8MB
  __hip_bfloat16* wfc1   = (__hip_bfloat16*)alloc((size_t)FFDIM * DMODEL * 2); // 32MB
  __hip_bfloat16* wfc2   = (__hip_bfloat16*)alloc((size_t)DMODEL * FFDIM * 2); // 32MB
  __hip_bfloat16* big    = (__hip_bfloat16*)alloc((size_t)TOK * FFDIM * 2);    // 64MB
  float*          x2     = (float*)alloc((size_t)TOK * DMODEL * 4);            // 32MB
  __hip_bfloat16* qkvbuf  = big;
  __hip_bfloat16* attnout = big + (size_t)TOK * TD;
  __hip_bfloat16* gelubuf = big;
  // FC2 split-K partials: reuse [xbf..wfc1) — all dead by FC2 time (16+24+8+32=80MB >= 64MB)
  float* pbuf = (float*)xbf;
  const long PSTRIDE = (long)TOK * DMODEL;

  f2bf_kernel<<<1024, 256, 0, stream>>>(qkvw,   wqkv,   (long)TD * DMODEL);
  f2bf_kernel<<<1024, 256, 0, stream>>>(densew, wdense, (long)DMODEL * DMODEL);
  f2bf_kernel<<<1024, 256, 0, stream>>>(fc1w,   wfc1,   (long)FFDIM * DMODEL);
  f2bf_kernel<<<1024, 256, 0, stream>>>(fc2w,   wfc2,   (long)DMODEL * FFDIM);

  ln_kernel<<<TOK, 256, 0, stream>>>(hidden, ln1w, ln1b, xbf);
  // QKV: 256x256, grid 24x16 = 384 blocks
  gemm256ra<0><<<dim3(TD / 256, TOK / 256, 1), 512, 0, stream>>>(
      xbf, wqkv, qkvb, nullptr, qkvbuf, TD, DMODEL, DMODEL, 0);
  attn_kernel<<<dim3(8, 2 * NHEAD), 256, 0, stream>>>(qkvbuf, attnout);
  // dense + residual: 256x128, grid 16x16 = 256 blocks
  gemm128ra<1><<<dim3(DMODEL / 128, TOK / 256), 512, 0, stream>>>(
      attnout, wdense, denseb, hidden, x2, DMODEL, DMODEL);
  ln_kernel<<<TOK, 256, 0, stream>>>(x2, ln2w, ln2b, xbf);
  // FC1 + GELU: 256x256, grid 32x16 = 512 blocks
  gemm256ra<2><<<dim3(FFDIM / 256, TOK / 256, 1), 512, 0, stream>>>(
      xbf, wfc1, fc1b, nullptr, gelubuf, FFDIM, DMODEL, DMODEL, 0);
  // FC2 split-K x2: 256x256, grid 8x16x2 = 256 blocks, Ksub=4096
  gemm256ra<3><<<dim3(DMODEL / 256, TOK / 256, 2), 512, 0, stream>>>(
      gelubuf, wfc2, nullptr, pbuf, nullptr, DMODEL, FFDIM / 2, FFDIM, PSTRIDE);
  // reduce: out = p0 + p1 + x2 + fc2b
  addred_kernel<<<(TOK * DMODEL) / 1024, 256, 0, stream>>>(
      pbuf, pbuf + PSTRIDE, x2, fc2b, (float*)d_out);
}